// Round 1
// baseline (1251.013 us; speedup 1.0000x reference)
//
#include <hip/hip_runtime.h>
#include <stdint.h>

typedef unsigned long long u64;
typedef unsigned int u32;

#define N_BOXES 50000
#define N_CLS 80
#define N_IMG 8
#define KCAND 500
#define MAX_DET 300
#define CAP 3072
#define PRE_THR 0.5f
#define KEPT_STRIDE 512

// workspace layout (bytes)
#define OFF_CANDCNT 0                       // 640 * 4
#define OFF_KEPTCNT 2560                    // 640 * 4
#define OFF_KEPTKEYS 8192                   // 640 * 512 * 8 = 2,621,440
#define OFF_CAND (8192 + 640 * 512 * 8)     // 640 * 3072 * 8 = 15,728,640

__device__ __forceinline__ int bin_of(u32 sb) {
  // scores in (0.5, 1]: bits in (0x3F000000, 0x3F800000]; 2048 bins of 4096 ulps
  int d = (int)(sb - 0x3F000000u);
  int bin = d < 0 ? 0 : (d >> 12);
  return bin > 2047 ? 2047 : bin;
}

// ---------------- kernel 1: candidate compaction ----------------
__global__ __launch_bounds__(256) void k1_compact(const float* __restrict__ cls,
                                                  int* __restrict__ candCnt,
                                                  u64* __restrict__ cand) {
  int b = blockIdx.y;
  int n = blockIdx.x * 256 + threadIdx.x;
  bool active = (n < N_BOXES);
  int lane = threadIdx.x & 63;
  size_t base = ((size_t)(b * N_BOXES + (active ? n : 0))) * N_CLS;
  u32 inv_n = ~(u32)n;
  for (int c4 = 0; c4 < N_CLS; c4 += 4) {
    float4 s4 = active ? *(const float4*)(cls + base + c4) : make_float4(0.f, 0.f, 0.f, 0.f);
    float ss[4] = {s4.x, s4.y, s4.z, s4.w};
#pragma unroll
    for (int q = 0; q < 4; ++q) {
      bool pred = active && (ss[q] > PRE_THR);
      u64 mask = __ballot(pred);
      if (mask) {
        int leader = __builtin_ctzll(mask);
        int cnt = __builtin_popcountll(mask);
        int basepos = 0;
        if (lane == leader) basepos = atomicAdd(&candCnt[b * N_CLS + c4 + q], cnt);
        basepos = __shfl(basepos, leader);
        if (pred) {
          int pos = basepos + __builtin_popcountll(mask & ((1ull << lane) - 1ull));
          if (pos < CAP)
            cand[(size_t)(b * N_CLS + c4 + q) * CAP + pos] =
                ((u64)__float_as_uint(ss[q]) << 32) | (u64)inv_n;
        }
      }
    }
  }
}

// ---------------- kernel 2: per-(b,c) top-500 + NMS ----------------
__global__ __launch_bounds__(256) void k2_class(const float* __restrict__ boxes,
                                                const int* __restrict__ candCnt,
                                                const u64* __restrict__ cand,
                                                int* __restrict__ keptCnt,
                                                u64* __restrict__ keptKeys) {
  __shared__ u32 hist[2048];
  __shared__ int partial[256];
  __shared__ u64 sbuf[1024];
  __shared__ float bx[512][4];
  __shared__ float areas[512];
  __shared__ u64 cols[512 * 8];
  __shared__ int s_t, s_cnt;

  int tid = threadIdx.x;
  int bc = blockIdx.x;
  int b = bc / N_CLS, c = bc % N_CLS;
  int m = candCnt[bc];
  if (m > CAP) m = CAP;
  const u64* my = cand + (size_t)bc * CAP;

  for (int i = tid; i < 2048; i += 256) hist[i] = 0;
  __syncthreads();
  for (int k = tid; k < m; k += 256) atomicAdd(&hist[bin_of((u32)(my[k] >> 32))], 1u);
  __syncthreads();
  int ps = 0;
#pragma unroll
  for (int q = 0; q < 8; ++q) ps += (int)hist[tid * 8 + q];
  partial[tid] = ps;
  __syncthreads();
  if (tid == 0) {
    int acc = 0, t = 0, p;
    for (p = 255; p >= 0; --p) {
      if (acc + partial[p] >= KCAND) break;
      acc += partial[p];
    }
    if (p >= 0) {
      int bin;
      for (bin = p * 8 + 7; bin > p * 8; --bin) {
        if (acc + (int)hist[bin] >= KCAND) break;
        acc += (int)hist[bin];
      }
      t = bin;
    }
    s_t = t;
    s_cnt = 0;
  }
  __syncthreads();
  int t = s_t;
  for (int k = tid; k < m; k += 256) {
    u64 key = my[k];
    if (bin_of((u32)(key >> 32)) >= t) {
      int p = atomicAdd(&s_cnt, 1);
      if (p < 1024) sbuf[p] = key;
    }
  }
  __syncthreads();
  int cnt = s_cnt;
  if (cnt > 1024) cnt = 1024;
  for (int i = tid; i < 1024; i += 256)
    if (i >= cnt) sbuf[i] = 0;
  // bitonic sort, descending by key
  for (int k = 2; k <= 1024; k <<= 1)
    for (int j = k >> 1; j > 0; j >>= 1) {
      __syncthreads();
      for (int i = tid; i < 1024; i += 256) {
        int l = i ^ j;
        if (l > i) {
          u64 a = sbuf[i], bb = sbuf[l];
          bool up = ((i & k) == 0);
          if (up ? (a < bb) : (a > bb)) { sbuf[i] = bb; sbuf[l] = a; }
        }
      }
    }
  __syncthreads();
  int V = cnt < KCAND ? cnt : KCAND;
  for (int i = tid; i < V; i += 256) {
    u32 n = ~((u32)sbuf[i]);
    const float* bp = boxes + ((size_t)b * N_BOXES + n) * 4;
    float b0 = bp[0], b1 = bp[1], b2 = bp[2], b3 = bp[3];
    bx[i][0] = b0; bx[i][1] = b1; bx[i][2] = b2; bx[i][3] = b3;
    areas[i] = __fmul_rn(fmaxf(__fsub_rn(b2, b0), 0.0f), fmaxf(__fsub_rn(b3, b1), 0.0f));
  }
  __syncthreads();
  // column-major suppression bitmask: cols[j*8+w] bit (i&63) == (i<j && iou(i,j)>0.5)
  for (int task = tid; task < 512 * 8; task += 256) {
    int j = task >> 3, w = task & 7;
    u64 bits = 0;
    int i0 = w * 64;
    if (j < V && i0 < j) {
      float bj0 = bx[j][0], bj1 = bx[j][1], bj2 = bx[j][2], bj3 = bx[j][3];
      float aj = areas[j];
      int imax = (j < i0 + 64) ? j : (i0 + 64);
      for (int i = i0; i < imax; ++i) {
        float yy1 = fmaxf(bx[i][0], bj0);
        float xx1 = fmaxf(bx[i][1], bj1);
        float yy2 = fminf(bx[i][2], bj2);
        float xx2 = fminf(bx[i][3], bj3);
        float ih = fmaxf(__fsub_rn(yy2, yy1), 0.0f);
        float iw = fmaxf(__fsub_rn(xx2, xx1), 0.0f);
        float inter = __fmul_rn(ih, iw);
        float denom = __fadd_rn(__fsub_rn(__fadd_rn(areas[i], aj), inter), 1e-9f);
        if (__fdiv_rn(inter, denom) > 0.5f) bits |= (1ull << (i & 63));
      }
    }
    cols[task] = bits;
  }
  __syncthreads();
  // greedy scan: wave 0, ballot-chunked (no LDS in the serial chain)
  if (tid < 64) {
    int lane = tid;
    u64 kmreg[8];
    int total = 0;
#pragma unroll
    for (int dst = 0; dst < 8; ++dst) {
      int gj = dst * 64 + lane;
      bool sup = false;
#pragma unroll
      for (int src = 0; src < dst; ++src)
        if (cols[gj * 8 + src] & kmreg[src]) sup = true;
      u64 colw = cols[gj * 8 + dst];
      u64 supmask = __ballot(sup);
      u64 keptm = 0;
      int lim = V - dst * 64;
      if (lim > 64) lim = 64;
      for (int i = 0; i < lim; ++i) {
        if (!((supmask >> i) & 1ull)) {
          keptm |= (1ull << i);
          supmask |= __ballot((int)((colw >> i) & 1ull));
        }
      }
      int rank = total + (int)__builtin_popcountll(keptm & ((1ull << lane) - 1ull));
      if (((keptm >> lane) & 1ull) && rank < MAX_DET) {
        u64 key = sbuf[gj];
        u32 sb = (u32)(key >> 32);
        u32 n = ~((u32)key);
        u32 flat = (u32)(c * KCAND + gj);
        keptKeys[(size_t)bc * KEPT_STRIDE + rank] =
            ((u64)sb << 32) | ((u64)((~flat) & 0xFFFFu) << 16) | (u64)(n & 0xFFFFu);
      }
      total += (int)__builtin_popcountll(keptm);
      kmreg[dst] = keptm;
    }
    if (lane == 0) keptCnt[bc] = total < MAX_DET ? total : MAX_DET;
  }
}

// ---------------- kernel 3: per-image global top-300 ----------------
__global__ __launch_bounds__(256) void k3_image(const float* __restrict__ boxes,
                                                const int* __restrict__ keptCnt,
                                                const u64* __restrict__ keptKeys,
                                                float* __restrict__ out) {
  __shared__ u32 hist[2048];
  __shared__ int partial[256];
  __shared__ u64 sbuf[1024];
  __shared__ int kcs[N_CLS];
  __shared__ int s_t, s_cnt;
  int tid = threadIdx.x;
  int b = blockIdx.x;
  for (int i = tid; i < 2048; i += 256) hist[i] = 0;
  if (tid < N_CLS) kcs[tid] = keptCnt[b * N_CLS + tid];
  __syncthreads();
  const u64* kk = keptKeys + (size_t)b * N_CLS * KEPT_STRIDE;
  for (int idx = tid; idx < N_CLS * KEPT_STRIDE; idx += 256) {
    int cc = idx >> 9, k = idx & 511;
    if (k < kcs[cc]) atomicAdd(&hist[bin_of((u32)(kk[(size_t)cc * KEPT_STRIDE + k] >> 32))], 1u);
  }
  __syncthreads();
  int ps = 0;
#pragma unroll
  for (int q = 0; q < 8; ++q) ps += (int)hist[tid * 8 + q];
  partial[tid] = ps;
  __syncthreads();
  if (tid == 0) {
    int acc = 0, t = 0, p;
    for (p = 255; p >= 0; --p) {
      if (acc + partial[p] >= MAX_DET) break;
      acc += partial[p];
    }
    if (p >= 0) {
      int bin;
      for (bin = p * 8 + 7; bin > p * 8; --bin) {
        if (acc + (int)hist[bin] >= MAX_DET) break;
        acc += (int)hist[bin];
      }
      t = bin;
    }
    s_t = t;
    s_cnt = 0;
  }
  __syncthreads();
  int t = s_t;
  for (int idx = tid; idx < N_CLS * KEPT_STRIDE; idx += 256) {
    int cc = idx >> 9, k = idx & 511;
    if (k < kcs[cc]) {
      u64 key = kk[(size_t)cc * KEPT_STRIDE + k];
      if (bin_of((u32)(key >> 32)) >= t) {
        int p = atomicAdd(&s_cnt, 1);
        if (p < 1024) sbuf[p] = key;
      }
    }
  }
  __syncthreads();
  int cnt = s_cnt;
  if (cnt > 1024) cnt = 1024;
  for (int i = tid; i < 1024; i += 256)
    if (i >= cnt) sbuf[i] = 0;
  for (int k = 2; k <= 1024; k <<= 1)
    for (int j = k >> 1; j > 0; j >>= 1) {
      __syncthreads();
      for (int i = tid; i < 1024; i += 256) {
        int l = i ^ j;
        if (l > i) {
          u64 a = sbuf[i], bb = sbuf[l];
          bool up = ((i & k) == 0);
          if (up ? (a < bb) : (a > bb)) { sbuf[i] = bb; sbuf[l] = a; }
        }
      }
    }
  __syncthreads();
  int V = cnt < MAX_DET ? cnt : MAX_DET;
  for (int s = tid; s < MAX_DET; s += 256) {
    float o0 = -1.f, o1 = -1.f, o2 = -1.f, o3 = -1.f, osc = -1.f, olb = -1.f;
    if (s < V) {
      u64 key = sbuf[s];
      u32 sb = (u32)(key >> 32);
      u32 flat = (~((u32)(key >> 16))) & 0xFFFFu;
      u32 n = (u32)key & 0xFFFFu;
      const float* bp = boxes + ((size_t)b * N_BOXES + n) * 4;
      o0 = bp[0]; o1 = bp[1]; o2 = bp[2]; o3 = bp[3];
      osc = __uint_as_float(sb);
      olb = (float)(flat / KCAND);
    }
    size_t bs = (size_t)b * MAX_DET + s;
    out[bs * 4 + 0] = o0;
    out[bs * 4 + 1] = o1;
    out[bs * 4 + 2] = o2;
    out[bs * 4 + 3] = o3;
    out[(size_t)N_IMG * MAX_DET * 4 + bs] = osc;
    out[(size_t)N_IMG * MAX_DET * 5 + bs] = olb;
  }
}

extern "C" void kernel_launch(void* const* d_in, const int* in_sizes, int n_in,
                              void* d_out, int out_size, void* d_ws, size_t ws_size,
                              hipStream_t stream) {
  const float* boxes = (const float*)d_in[0];
  const float* cls = (const float*)d_in[1];
  float* out = (float*)d_out;
  char* ws = (char*)d_ws;
  int* candCnt = (int*)(ws + OFF_CANDCNT);
  int* keptCnt = (int*)(ws + OFF_KEPTCNT);
  u64* keptKeys = (u64*)(ws + OFF_KEPTKEYS);
  u64* cand = (u64*)(ws + OFF_CAND);

  hipMemsetAsync(ws, 0, 5120, stream);  // zero both counter arrays

  dim3 g1((N_BOXES + 255) / 256, N_IMG);
  k1_compact<<<g1, 256, 0, stream>>>(cls, candCnt, cand);
  k2_class<<<N_IMG * N_CLS, 256, 0, stream>>>(boxes, candCnt, cand, keptCnt, keptKeys);
  k3_image<<<N_IMG, 256, 0, stream>>>(boxes, keptCnt, keptKeys, out);
}